// Round 4
// baseline (265.193 us; speedup 1.0000x reference)
//
#include <hip/hip_runtime.h>
#include <hip/hip_bf16.h>

#define DPROJ 1024

typedef float  f32x4  __attribute__((ext_vector_type(4)));
typedef short  bf16x8 __attribute__((ext_vector_type(8)));

__device__ __forceinline__ unsigned pk2(float a, float b) {
    __hip_bfloat162 h = __float22bfloat162_rn(make_float2(a, b));
    unsigned r; __builtin_memcpy(&r, &h, 4); return r;
}

// ---------------- pass 1: classify + proj->bf16 convert ---------------------
// Blocks [0, CB): classify n tokens (wave-aggregated atomic compaction; list
// order nondeterministic but per-token output is order-independent).
// Blocks [CB, CB+688): convert proj tables fp32 -> bf16. pb3 is written with
// row stride 32 (k 16..31 zero-padded) so k_gemm's uniform KC=32 loop never
// reads out of bounds for z=3.
__global__ __launch_bounds__(256) void k_prep(
    const int* __restrict__ inp, int n,
    int* __restrict__ cnt, int* __restrict__ lists,
    const float* __restrict__ p0, const float* __restrict__ p1,
    const float* __restrict__ p2, const float* __restrict__ p3,
    short* __restrict__ pb0, short* __restrict__ pb1,
    short* __restrict__ pb2, short* __restrict__ pb3)
{
    const int tid = threadIdx.x;
    const int b   = blockIdx.x;
    const int CB  = (n + 255) >> 8;
    if (b < CB) {
        const int t = b * 256 + tid;
        int c = -1, l = 0;
        if (t < n) {
            const int x = inp[t];
            c = (x >= 20000) + (x >= 40000) + (x >= 200000);
            l = x - ((c == 0) ? 0 : (c == 1) ? 20000 : (c == 2) ? 40000 : 200000);
        }
        const int lane = tid & 63;
        int pos = 0;
        #pragma unroll
        for (int cc = 0; cc < 4; ++cc) {
            const unsigned long long mk = __ballot(c == cc);
            if (c == cc) {
                const int lead = __ffsll(mk) - 1;
                int base = 0;
                if (lane == lead) base = atomicAdd(&cnt[cc], (int)__popcll(mk));
                base = __shfl(base, lead);
                pos  = base + (int)__popcll(mk & ((1ull << lane) - 1ull));
            }
        }
        if (t < n) lists[c * n + pos] = (int)(((unsigned)t << 18) | (unsigned)l);
    } else {
        // chunk = 8 floats. pb0:131072  pb1:32768  pb2:8192  pb3:4096(padded)
        const long g = (long)(b - CB) * 256 + tid;
        if (g < 172032) {
            const float* src; short* dst; long lo;
            if      (g < 131072) { src = p0; dst = pb0; lo = g; }
            else if (g < 163840) { src = p1; dst = pb1; lo = g - 131072; }
            else                 { src = p2; dst = pb2; lo = g - 163840; }
            const float4 a = *(const float4*)(src + lo * 8);
            const float4 d = *(const float4*)(src + lo * 8 + 4);
            uint4 q; q.x = pk2(a.x, a.y); q.y = pk2(a.z, a.w);
                     q.z = pk2(d.x, d.y); q.w = pk2(d.z, d.w);
            *(uint4*)(dst + lo * 8) = q;
        } else if (g < 176128) {
            const long lo = g - 172032;           // 0..4095
            const int col = (int)(lo >> 2), c = (int)(lo & 3);
            uint4 q = (uint4){0u, 0u, 0u, 0u};
            if (c < 2) {
                const float* src = p3 + (size_t)col * 16 + c * 8;
                const float4 a = *(const float4*)src;
                const float4 d = *(const float4*)(src + 4);
                q.x = pk2(a.x, a.y); q.y = pk2(a.z, a.w);
                q.z = pk2(d.x, d.y); q.w = pk2(d.z, d.w);
            }
            *(uint4*)(pb3 + (size_t)col * 32 + c * 8) = q;
        }
    }
}

// ---------------- pass 2: gather used E rows -> compact bf16 (LINEAR) -------
// ec layout: cluster-contiguous, row r of cluster z at ec + off_z + r*Kpad
// (Kpad = 1024/256/64/32; z=3 zero-padded k 16..31). Linear storage: k_gemm
// now loads fragments straight to registers, no LDS, so no swizzle.
__global__ __launch_bounds__(256) void k_egather(
    const int* __restrict__ cnt, const int* __restrict__ lists, int n,
    const float* __restrict__ e0, const float* __restrict__ e1,
    const float* __restrict__ e2, const float* __restrict__ e3,
    short* __restrict__ ec)
{
    const int c0 = cnt[0], c1 = cnt[1], c2 = cnt[2], c3 = cnt[3];
    const long t0 = (long)c0 * 128;          // chunks/row: 128, 32, 8, 4
    const long t1 = t0 + (long)c1 * 32;
    const long t2 = t1 + (long)c2 * 8;
    const long t3 = t2 + (long)c3 * 4;
    const long o1 = (long)c0 * 1024;         // ec offsets in shorts
    const long o2 = o1 + (long)c1 * 256;
    const long o3 = o2 + (long)c2 * 64;

    const long stride = (long)gridDim.x * 256;
    for (long i = (long)blockIdx.x * 256 + threadIdx.x; i < t3; i += stride) {
        int z, Kp, Kr, lc; long rem, off; const float* emb;
        if (i < t0)      { z = 0; rem = i;      off = 0;  emb = e0; Kp = 1024; Kr = 1024; lc = 7; }
        else if (i < t1) { z = 1; rem = i - t0; off = o1; emb = e1; Kp = 256;  Kr = 256;  lc = 5; }
        else if (i < t2) { z = 2; rem = i - t1; off = o2; emb = e2; Kp = 64;   Kr = 64;   lc = 3; }
        else             { z = 3; rem = i - t2; off = o3; emb = e3; Kp = 32;   Kr = 16;   lc = 2; }
        const int r = (int)(rem >> lc);
        const int c = (int)(rem & ((1 << lc) - 1));
        const int k = c * 8;
        uint4 q = (uint4){0u, 0u, 0u, 0u};
        if (k < Kr) {
            const int loc = lists[z * n + r] & 0x3FFFF;
            const float* src = emb + (size_t)loc * Kr + k;
            const float4 a = *(const float4*)src;
            const float4 d = *(const float4*)(src + 4);
            q.x = pk2(a.x, a.y); q.y = pk2(a.z, a.w);
            q.z = pk2(d.x, d.y); q.w = pk2(d.z, d.w);
        }
        *(uint4*)(ec + off + (size_t)r * Kp + c * 8) = q;
    }
}

// ---------------- pass 3: LDS-free, barrier-free bf16-MFMA GEMM -------------
// r3 post-mortem: two different schedulers both stalled ~25 us/tile at the
// per-K-step __syncthreads() vmcnt(0) drain (8 MFMAs can't cover ~500cy load
// latency; 4 waves convoy at the barrier). Fix: fragments load STRAIGHT from
// global to registers -- with swapped operands each lane's frag is a natural
// contiguous 16B load (A: pb[(col+lm)*Kp + quad*8], B: ec[(row+lm)*Kp + ..]),
// sector-aligned 64B chunks across the wave. Wave owns 32 cols x 64 rows:
// P read once per block (no dup), E 4x (tiny, L2-hot). Register double-buffer,
// ZERO barriers / LDS / atomics -> latency hidden by MLP x TLP, no convoy.
__global__ __launch_bounds__(256, 4) void k_gemm(
    const int* __restrict__ cnt, const int* __restrict__ lists, int n,
    const short* __restrict__ ec,
    const short* __restrict__ pb0, const short* __restrict__ pb1,
    const short* __restrict__ pb2, const short* __restrict__ pb3,
    float* __restrict__ out)
{
    const int yb = blockIdx.x, z = blockIdx.y, xb = blockIdx.z;
    const int c0 = cnt[0], c1 = cnt[1], c2 = cnt[2], c3 = cnt[3];
    const int count = (z == 0) ? c0 : (z == 1) ? c1 : (z == 2) ? c2 : c3;
    const int row0  = yb * 64;
    if (row0 >= count) return;

    const short* pb = (z == 0) ? pb0 : (z == 1) ? pb1 : (z == 2) ? pb2 : pb3;
    const int    Kp = (z == 0) ? 1024 : (z == 1) ? 256 : (z == 2) ? 64 : 32;
    const long eoff = (z == 0) ? 0
                    : (z == 1) ? (long)c0 * 1024
                    : (z == 2) ? (long)c0 * 1024 + (long)c1 * 256
                               : (long)c0 * 1024 + (long)c1 * 256 + (long)c2 * 64;
    const int nt    = Kp >> 5;
    const int* list = lists + (size_t)z * n;

    const int tid  = threadIdx.x;
    const int wave = tid >> 6, lane = tid & 63;
    const int lm = lane & 15, quad = lane >> 4;
    const int colA = xb * 128 + wave * 32;      // this wave's 32 proj cols

    // tokens for the 4 row-groups this lane stores (col of D = lm)
    int tk0, tk1, tk2, tk3;
    {
        const int r0 = row0 + lm, r1 = r0 + 16, r2 = r0 + 32, r3 = r0 + 48;
        tk0 = (r0 < count) ? (int)((unsigned)list[r0] >> 18) : -1;
        tk1 = (r1 < count) ? (int)((unsigned)list[r1] >> 18) : -1;
        tk2 = (r2 < count) ? (int)((unsigned)list[r2] >> 18) : -1;
        tk3 = (r3 < count) ? (int)((unsigned)list[r3] >> 18) : -1;
    }

    // per-lane fragment pointers; +32 shorts (64 B) per K-step
    const short* pa0 = pb + (size_t)(colA +      lm) * Kp + quad * 8;
    const short* pa1 = pb + (size_t)(colA + 16 + lm) * Kp + quad * 8;
    const int rc = count - 1;
    int e0r = row0 + lm,      e1r = row0 + 16 + lm;
    int e2r = row0 + 32 + lm, e3r = row0 + 48 + lm;
    if (e0r > rc) e0r = rc;  if (e1r > rc) e1r = rc;
    if (e2r > rc) e2r = rc;  if (e3r > rc) e3r = rc;
    const short* pe0 = ec + eoff + (size_t)e0r * Kp + quad * 8;
    const short* pe1 = ec + eoff + (size_t)e1r * Kp + quad * 8;
    const short* pe2 = ec + eoff + (size_t)e2r * Kp + quad * 8;
    const short* pe3 = ec + eoff + (size_t)e3r * Kp + quad * 8;

    f32x4 acc00 = {0,0,0,0}, acc01 = {0,0,0,0};
    f32x4 acc10 = {0,0,0,0}, acc11 = {0,0,0,0};
    f32x4 acc20 = {0,0,0,0}, acc21 = {0,0,0,0};
    f32x4 acc30 = {0,0,0,0}, acc31 = {0,0,0,0};

    #define LD8(p) (*(const bf16x8*)(p))
    // cur frags
    bf16x8 a0 = LD8(pa0), a1 = LD8(pa1);
    bf16x8 b0 = LD8(pe0), b1 = LD8(pe1), b2 = LD8(pe2), b3 = LD8(pe3);

    for (int t = 0; t + 1 < nt; ++t) {
        pa0 += 32; pa1 += 32; pe0 += 32; pe1 += 32; pe2 += 32; pe3 += 32;
        // issue next-step loads (1-deep register pipeline, 6 loads in flight)
        bf16x8 na0 = LD8(pa0), na1 = LD8(pa1);
        bf16x8 nb0 = LD8(pe0), nb1 = LD8(pe1), nb2 = LD8(pe2), nb3 = LD8(pe3);
        // MFMAs on cur
        acc00 = __builtin_amdgcn_mfma_f32_16x16x32_bf16(a0, b0, acc00, 0, 0, 0);
        acc01 = __builtin_amdgcn_mfma_f32_16x16x32_bf16(a1, b0, acc01, 0, 0, 0);
        acc10 = __builtin_amdgcn_mfma_f32_16x16x32_bf16(a0, b1, acc10, 0, 0, 0);
        acc11 = __builtin_amdgcn_mfma_f32_16x16x32_bf16(a1, b1, acc11, 0, 0, 0);
        acc20 = __builtin_amdgcn_mfma_f32_16x16x32_bf16(a0, b2, acc20, 0, 0, 0);
        acc21 = __builtin_amdgcn_mfma_f32_16x16x32_bf16(a1, b2, acc21, 0, 0, 0);
        acc30 = __builtin_amdgcn_mfma_f32_16x16x32_bf16(a0, b3, acc30, 0, 0, 0);
        acc31 = __builtin_amdgcn_mfma_f32_16x16x32_bf16(a1, b3, acc31, 0, 0, 0);
        a0 = na0; a1 = na1; b0 = nb0; b1 = nb1; b2 = nb2; b3 = nb3;
    }
    acc00 = __builtin_amdgcn_mfma_f32_16x16x32_bf16(a0, b0, acc00, 0, 0, 0);
    acc01 = __builtin_amdgcn_mfma_f32_16x16x32_bf16(a1, b0, acc01, 0, 0, 0);
    acc10 = __builtin_amdgcn_mfma_f32_16x16x32_bf16(a0, b1, acc10, 0, 0, 0);
    acc11 = __builtin_amdgcn_mfma_f32_16x16x32_bf16(a1, b1, acc11, 0, 0, 0);
    acc20 = __builtin_amdgcn_mfma_f32_16x16x32_bf16(a0, b2, acc20, 0, 0, 0);
    acc21 = __builtin_amdgcn_mfma_f32_16x16x32_bf16(a1, b2, acc21, 0, 0, 0);
    acc30 = __builtin_amdgcn_mfma_f32_16x16x32_bf16(a0, b3, acc30, 0, 0, 0);
    acc31 = __builtin_amdgcn_mfma_f32_16x16x32_bf16(a1, b3, acc31, 0, 0, 0);
    #undef LD8

    // epilogue: D row = proj col (quad*4+reg), D col = token (lm)
    // lane stores cols colA + ns*16 + quad*4 .. +4 for its 4 tokens
    const int cbase = colA + quad * 4;
    #define ST(tk, A0, A1)                                               \
        if ((tk) >= 0) {                                                 \
            float* orow = out + (size_t)(tk) * DPROJ + cbase;            \
            *(f32x4*)(orow)      = A0 * 32.f;                            \
            *(f32x4*)(orow + 16) = A1 * 32.f;                            \
        }
    ST(tk0, acc00, acc01)
    ST(tk1, acc10, acc11)
    ST(tk2, acc20, acc21)
    ST(tk3, acc30, acc31)
    #undef ST
}

extern "C" void kernel_launch(void* const* d_in, const int* in_sizes, int n_in,
                              void* d_out, int out_size, void* d_ws, size_t ws_size,
                              hipStream_t stream) {
    const int*   inp = (const int*)d_in[0];
    const float* e0  = (const float*)d_in[1];
    const float* p0  = (const float*)d_in[2];
    const float* e1  = (const float*)d_in[3];
    const float* p1  = (const float*)d_in[4];
    const float* e2  = (const float*)d_in[5];
    const float* p2  = (const float*)d_in[6];
    const float* e3  = (const float*)d_in[7];
    const float* p3  = (const float*)d_in[8];
    float* out = (float*)d_out;
    const int n = in_sizes[0];  // 16384 tokens

    // ws: cnt[4] pad | lists[4n] | pb0..pb3 (pb3 stride-32 padded) | ec
    char* wsb  = (char*)d_ws;
    int* cnt   = (int*)wsb;
    int* lists = (int*)(wsb + 32);
    size_t off = 32 + (size_t)4 * n * sizeof(int);
    off = (off + 255) & ~(size_t)255;
    short* pb0 = (short*)(wsb + off); off += (size_t)1024 * 1024 * 2;
    short* pb1 = (short*)(wsb + off); off += (size_t)1024 * 256 * 2;
    short* pb2 = (short*)(wsb + off); off += (size_t)1024 * 64 * 2;
    short* pb3 = (short*)(wsb + off); off += (size_t)1024 * 32 * 2;
    short* ec  = (short*)(wsb + off);   // compact E, ~4.7 MB for this dist

    hipMemsetAsync(cnt, 0, 32, stream);

    const int CB = (n + 255) >> 8;
    k_prep<<<CB + 688, 256, 0, stream>>>(inp, n, cnt, lists,
                                         p0, p1, p2, p3, pb0, pb1, pb2, pb3);
    k_egather<<<1024, 256, 0, stream>>>(cnt, lists, n, e0, e1, e2, e3, ec);

    dim3 grid((n + 63) / 64, 4, 8);     // (y, z, x): y fastest -> XCD co-location
    k_gemm<<<grid, 256, 0, stream>>>(cnt, lists, n, ec,
                                     pb0, pb1, pb2, pb3, out);
}

// Round 6
// 223.958 us; speedup vs baseline: 1.1841x; 1.1841x over previous
//
#include <hip/hip_runtime.h>
#include <hip/hip_bf16.h>

#define DPROJ 1024

typedef float  f32x4  __attribute__((ext_vector_type(4)));
typedef short  bf16x8 __attribute__((ext_vector_type(8)));

__device__ __forceinline__ unsigned pk2(float a, float b) {
    __hip_bfloat162 h = __float22bfloat162_rn(make_float2(a, b));
    unsigned r; __builtin_memcpy(&r, &h, 4); return r;
}

// async global->LDS, 16B per lane. LDS dest = wave-uniform base + lane*16;
// global src is PER-LANE.
__device__ __forceinline__ void gll16(const void* g, void* l) {
    __builtin_amdgcn_global_load_lds(
        (const __attribute__((address_space(1))) void*)g,
        (__attribute__((address_space(3))) void*)l, 16, 0, 0);
}

// ---------------- pass 1: classify + proj->bf16 convert ---------------------
__global__ __launch_bounds__(256) void k_prep(
    const int* __restrict__ inp, int n,
    int* __restrict__ cnt, int* __restrict__ lists,
    const float* __restrict__ p0, const float* __restrict__ p1,
    const float* __restrict__ p2, const float* __restrict__ p3,
    short* __restrict__ pb0, short* __restrict__ pb1,
    short* __restrict__ pb2, short* __restrict__ pb3)
{
    const int tid = threadIdx.x;
    const int b   = blockIdx.x;
    const int CB  = (n + 255) >> 8;
    if (b < CB) {
        const int t = b * 256 + tid;
        int c = -1, l = 0;
        if (t < n) {
            const int x = inp[t];
            c = (x >= 20000) + (x >= 40000) + (x >= 200000);
            l = x - ((c == 0) ? 0 : (c == 1) ? 20000 : (c == 2) ? 40000 : 200000);
        }
        const int lane = tid & 63;
        int pos = 0;
        #pragma unroll
        for (int cc = 0; cc < 4; ++cc) {
            const unsigned long long mk = __ballot(c == cc);
            if (c == cc) {
                const int lead = __ffsll(mk) - 1;
                int base = 0;
                if (lane == lead) base = atomicAdd(&cnt[cc], (int)__popcll(mk));
                base = __shfl(base, lead);
                pos  = base + (int)__popcll(mk & ((1ull << lane) - 1ull));
            }
        }
        if (t < n) lists[c * n + pos] = (int)(((unsigned)t << 18) | (unsigned)l);
    } else {
        // chunk = 8 floats. pb0:131072  pb1:32768  pb2:8192  pb3:4096(padded)
        const long g = (long)(b - CB) * 256 + tid;
        if (g < 172032) {
            const float* src; short* dst; long lo;
            if      (g < 131072) { src = p0; dst = pb0; lo = g; }
            else if (g < 163840) { src = p1; dst = pb1; lo = g - 131072; }
            else                 { src = p2; dst = pb2; lo = g - 163840; }
            const float4 a = *(const float4*)(src + lo * 8);
            const float4 d = *(const float4*)(src + lo * 8 + 4);
            uint4 q; q.x = pk2(a.x, a.y); q.y = pk2(a.z, a.w);
                     q.z = pk2(d.x, d.y); q.w = pk2(d.z, d.w);
            *(uint4*)(dst + lo * 8) = q;
        } else if (g < 176128) {
            const long lo = g - 172032;           // 0..4095
            const int col = (int)(lo >> 2), c = (int)(lo & 3);
            uint4 q = (uint4){0u, 0u, 0u, 0u};
            if (c < 2) {
                const float* src = p3 + (size_t)col * 16 + c * 8;
                const float4 a = *(const float4*)src;
                const float4 d = *(const float4*)(src + 4);
                q.x = pk2(a.x, a.y); q.y = pk2(a.z, a.w);
                q.z = pk2(d.x, d.y); q.w = pk2(d.z, d.w);
            }
            *(uint4*)(pb3 + (size_t)col * 32 + c * 8) = q;
        }
    }
}

// ---------------- pass 2: gather used E rows -> compact bf16 (linear) -------
__global__ __launch_bounds__(256) void k_egather(
    const int* __restrict__ cnt, const int* __restrict__ lists, int n,
    const float* __restrict__ e0, const float* __restrict__ e1,
    const float* __restrict__ e2, const float* __restrict__ e3,
    short* __restrict__ ec)
{
    const int c0 = cnt[0], c1 = cnt[1], c2 = cnt[2], c3 = cnt[3];
    const long t0 = (long)c0 * 128;          // chunks/row: 128, 32, 8, 4
    const long t1 = t0 + (long)c1 * 32;
    const long t2 = t1 + (long)c2 * 8;
    const long t3 = t2 + (long)c3 * 4;
    const long o1 = (long)c0 * 1024;         // ec offsets in shorts
    const long o2 = o1 + (long)c1 * 256;
    const long o3 = o2 + (long)c2 * 64;

    const long stride = (long)gridDim.x * 256;
    for (long i = (long)blockIdx.x * 256 + threadIdx.x; i < t3; i += stride) {
        int z, Kp, Kr, lc; long rem, off; const float* emb;
        if (i < t0)      { z = 0; rem = i;      off = 0;  emb = e0; Kp = 1024; Kr = 1024; lc = 7; }
        else if (i < t1) { z = 1; rem = i - t0; off = o1; emb = e1; Kp = 256;  Kr = 256;  lc = 5; }
        else if (i < t2) { z = 2; rem = i - t1; off = o2; emb = e2; Kp = 64;   Kr = 64;   lc = 3; }
        else             { z = 3; rem = i - t2; off = o3; emb = e3; Kp = 32;   Kr = 16;   lc = 2; }
        const int r = (int)(rem >> lc);
        const int c = (int)(rem & ((1 << lc) - 1));
        const int k = c * 8;
        uint4 q = (uint4){0u, 0u, 0u, 0u};
        if (k < Kr) {
            const int loc = lists[z * n + r] & 0x3FFFF;
            const float* src = emb + (size_t)loc * Kr + k;
            const float4 a = *(const float4*)src;
            const float4 d = *(const float4*)(src + 4);
            q.x = pk2(a.x, a.y); q.y = pk2(a.z, a.w);
            q.z = pk2(d.x, d.y); q.w = pk2(d.z, d.w);
        }
        *(uint4*)(ec + off + (size_t)r * Kp + c * 8) = q;
    }
}

// ---------------- pass 3: square-wave-tile pipelined bf16-MFMA GEMM ---------
// r5 post-mortem: counted vmcnt is PER-WAVE but LDS deps are CROSS-WAVE
// (wave q writes the kgroup that all waves read at quad==q) -> racing NaN.
// Correct invariant (m201 pattern): certify OWN writes BEFORE the barrier.
// Per K-step:
//   issue next loads -> s_waitcnt vmcnt(5) -> s_barrier   (RAW: cur complete)
//   ds_read cur + MFMA
//   s_waitcnt lgkmcnt(0) -> s_barrier                     (WAR: reads done)
// Next-step loads stay in flight across the whole step (never vmcnt(0) in
// the main loop). Wave tile 64x64: 8 ds_read_b128 -> 16 MFMAs (512 B/MFMA).
// LDS [kgroup][row] layout: b128 reads are 2-way max (free). Exact grid,
// z=0 (K=1024) tiles dispatched first. launch_bounds(256,2): NO spills --
// scratch ops would count in vmcnt and corrupt the count-5 logic.
__global__ __launch_bounds__(256, 2) void k_gemm(
    const int* __restrict__ cnt, const int* __restrict__ lists, int n,
    const short* __restrict__ ec,
    const short* __restrict__ pb0, const short* __restrict__ pb1,
    const short* __restrict__ pb2, const short* __restrict__ pb3,
    float* __restrict__ out)
{
    const int c0 = cnt[0], c1 = cnt[1], c2 = cnt[2], c3 = cnt[3];
    const int T0 = (c0 + 63) >> 6, T1 = (c1 + 63) >> 6;
    const int T2 = (c2 + 63) >> 6, T3 = (c3 + 63) >> 6;
    const int xb = (int)blockIdx.x & 3;
    const int gy = (int)blockIdx.x >> 2;
    if (gy >= T0 + T1 + T2 + T3) return;

    int z, yb;
    if      (gy < T0)           { z = 0; yb = gy; }
    else if (gy < T0 + T1)      { z = 1; yb = gy - T0; }
    else if (gy < T0 + T1 + T2) { z = 2; yb = gy - T0 - T1; }
    else                        { z = 3; yb = gy - T0 - T1 - T2; }

    const int count = (z == 0) ? c0 : (z == 1) ? c1 : (z == 2) ? c2 : c3;
    const int Kp    = (z == 0) ? 1024 : (z == 1) ? 256 : (z == 2) ? 64 : 32;
    const short* pb = (z == 0) ? pb0 : (z == 1) ? pb1 : (z == 2) ? pb2 : pb3;
    const long eoff = (z == 0) ? 0
                    : (z == 1) ? (long)c0 * 1024
                    : (z == 2) ? (long)c0 * 1024 + (long)c1 * 256
                               : (long)c0 * 1024 + (long)c1 * 256 + (long)c2 * 64;
    const int nt   = Kp >> 5;               // 32 / 8 / 2 / 1
    const int row0 = yb * 64, col0 = xb * 256;
    const int* list = lists + (size_t)z * n;

    // [buf][kgroup][row] 16B units; 8 + 32 KiB = 40 KiB total -> 4 blocks/CU
    __shared__ __align__(16) short e_s[2 * 2048];
    __shared__ __align__(16) short p_s[2 * 8192];

    const int tid = threadIdx.x;
    const int wave = tid >> 6, lane = tid & 63;
    const int lm = lane & 15, quad = lane >> 4;

    // E staging: wave w = kgroup w, lane l -> row l (clamped to valid)
    int er = row0 + lane; const int rc = count - 1; if (er > rc) er = rc;
    const short* esrc = ec + eoff + (size_t)er * Kp + wave * 8;
    // P staging: wave w = kgroup w; 4 issues of 64 cols each
    const short* ps0 = pb + (size_t)(col0 +       lane) * Kp + wave * 8;
    const short* ps1 = pb + (size_t)(col0 +  64 + lane) * Kp + wave * 8;
    const short* ps2 = pb + (size_t)(col0 + 128 + lane) * Kp + wave * 8;
    const short* ps3 = pb + (size_t)(col0 + 192 + lane) * Kp + wave * 8;

    f32x4 acc[4][4];    // [a = 16-col group][b = 16-row group]
    #pragma unroll
    for (int a = 0; a < 4; ++a)
        #pragma unroll
        for (int b = 0; b < 4; ++b) acc[a][b] = (f32x4){0.f, 0.f, 0.f, 0.f};

    // prologue: stage step 0 into buf 0 (5 gll16 per wave)
    gll16(esrc, e_s + wave * 512);
    gll16(ps0,  p_s + wave * 2048);
    gll16(ps1,  p_s + wave * 2048 + 512);
    gll16(ps2,  p_s + wave * 2048 + 1024);
    gll16(ps3,  p_s + wave * 2048 + 1536);

    for (int t = 0; t < nt; ++t) {
        const int cur = t & 1;
        if (t + 1 < nt) {
            const int kb = (t + 1) * 32;
            const int nb = cur ^ 1;
            gll16(esrc + kb, e_s + nb * 2048 + wave * 512);
            gll16(ps0  + kb, p_s + nb * 8192 + wave * 2048);
            gll16(ps1  + kb, p_s + nb * 8192 + wave * 2048 + 512);
            gll16(ps2  + kb, p_s + nb * 8192 + wave * 2048 + 1024);
            gll16(ps3  + kb, p_s + nb * 8192 + wave * 2048 + 1536);
            // own cur-step writes done (oldest 5); next 5 stay in flight
            asm volatile("s_waitcnt vmcnt(5)" ::: "memory");
        } else {
            asm volatile("s_waitcnt vmcnt(0)" ::: "memory");
        }
        __builtin_amdgcn_s_barrier();           // all waves' cur writes visible
        __builtin_amdgcn_sched_barrier(0);

        const short* eb = e_s + cur * 2048 + quad * 512 + lm * 8;
        const short* pa = p_s + cur * 8192 + quad * 2048 + wave * 512 + lm * 8;
        bf16x8 B0 = *(const bf16x8*)(eb);
        bf16x8 B1 = *(const bf16x8*)(eb + 128);
        bf16x8 B2 = *(const bf16x8*)(eb + 256);
        bf16x8 B3 = *(const bf16x8*)(eb + 384);
        bf16x8 A0 = *(const bf16x8*)(pa);
        bf16x8 A1 = *(const bf16x8*)(pa + 128);
        bf16x8 A2 = *(const bf16x8*)(pa + 256);
        bf16x8 A3 = *(const bf16x8*)(pa + 384);

        acc[0][0] = __builtin_amdgcn_mfma_f32_16x16x32_bf16(A0, B0, acc[0][0], 0, 0, 0);
        acc[1][0] = __builtin_amdgcn_mfma_f32_16x16x32_bf16(A1, B0, acc[1][0], 0, 0, 0);
        acc[2][0] = __builtin_amdgcn_mfma_f32_16x16x32_bf16(A2, B0, acc[2][0], 0, 0, 0);
        acc[3][0] = __builtin_amdgcn_mfma_f32_16x16x32_bf16(A3, B0, acc[3][0], 0, 0, 0);
        acc[0][1] = __builtin_amdgcn_mfma_f32_16x16x32_bf16(A0, B1, acc[0][1], 0, 0, 0);
        acc[1][1] = __builtin_amdgcn_mfma_f32_16x16x32_bf16(A1, B1, acc[1][1], 0, 0, 0);
        acc[2][1] = __builtin_amdgcn_mfma_f32_16x16x32_bf16(A2, B1, acc[2][1], 0, 0, 0);
        acc[3][1] = __builtin_amdgcn_mfma_f32_16x16x32_bf16(A3, B1, acc[3][1], 0, 0, 0);
        acc[0][2] = __builtin_amdgcn_mfma_f32_16x16x32_bf16(A0, B2, acc[0][2], 0, 0, 0);
        acc[1][2] = __builtin_amdgcn_mfma_f32_16x16x32_bf16(A1, B2, acc[1][2], 0, 0, 0);
        acc[2][2] = __builtin_amdgcn_mfma_f32_16x16x32_bf16(A2, B2, acc[2][2], 0, 0, 0);
        acc[3][2] = __builtin_amdgcn_mfma_f32_16x16x32_bf16(A3, B2, acc[3][2], 0, 0, 0);
        acc[0][3] = __builtin_amdgcn_mfma_f32_16x16x32_bf16(A0, B3, acc[0][3], 0, 0, 0);
        acc[1][3] = __builtin_amdgcn_mfma_f32_16x16x32_bf16(A1, B3, acc[1][3], 0, 0, 0);
        acc[2][3] = __builtin_amdgcn_mfma_f32_16x16x32_bf16(A2, B3, acc[2][3], 0, 0, 0);
        acc[3][3] = __builtin_amdgcn_mfma_f32_16x16x32_bf16(A3, B3, acc[3][3], 0, 0, 0);

        if (t + 1 < nt) {
            // WAR: own ds_reads done (free -- MFMA waits imply it), then
            // barrier so no wave overwrites a buffer others still read.
            asm volatile("s_waitcnt lgkmcnt(0)" ::: "memory");
            __builtin_amdgcn_sched_barrier(0);
            __builtin_amdgcn_s_barrier();
            __builtin_amdgcn_sched_barrier(0);
        }
    }

    // epilogue: D row = proj col (quad*4+reg), D col = token (lm)
    const int colW = col0 + wave * 64 + quad * 4;
    #pragma unroll
    for (int b = 0; b < 4; ++b) {
        const int r = row0 + b * 16 + lm;
        if (r < count) {
            const int tok = (int)((unsigned)list[r] >> 18);
            float* orow = out + (size_t)tok * DPROJ + colW;
            #pragma unroll
            for (int a = 0; a < 4; ++a)
                *(f32x4*)(orow + a * 16) = acc[a][b] * 32.f;
        }
    }
}

extern "C" void kernel_launch(void* const* d_in, const int* in_sizes, int n_in,
                              void* d_out, int out_size, void* d_ws, size_t ws_size,
                              hipStream_t stream) {
    const int*   inp = (const int*)d_in[0];
    const float* e0  = (const float*)d_in[1];
    const float* p0  = (const float*)d_in[2];
    const float* e1  = (const float*)d_in[3];
    const float* p1  = (const float*)d_in[4];
    const float* e2  = (const float*)d_in[5];
    const float* p2  = (const float*)d_in[6];
    const float* e3  = (const float*)d_in[7];
    const float* p3  = (const float*)d_in[8];
    float* out = (float*)d_out;
    const int n = in_sizes[0];  // 16384 tokens

    // ws: cnt[4] pad | lists[4n] | pb0..pb3 (pb3 stride-32 padded) | ec
    char* wsb  = (char*)d_ws;
    int* cnt   = (int*)wsb;
    int* lists = (int*)(wsb + 32);
    size_t off = 32 + (size_t)4 * n * sizeof(int);
    off = (off + 255) & ~(size_t)255;
    short* pb0 = (short*)(wsb + off); off += (size_t)1024 * 1024 * 2;
    short* pb1 = (short*)(wsb + off); off += (size_t)1024 * 256 * 2;
    short* pb2 = (short*)(wsb + off); off += (size_t)1024 * 64 * 2;
    short* pb3 = (short*)(wsb + off); off += (size_t)1024 * 32 * 2;
    short* ec  = (short*)(wsb + off);   // compact E, ~4.7 MB for this dist

    hipMemsetAsync(cnt, 0, 32, stream);

    const int CB = (n + 255) >> 8;
    k_prep<<<CB + 688, 256, 0, stream>>>(inp, n, cnt, lists,
                                         p0, p1, p2, p3, pb0, pb1, pb2, pb3);
    k_egather<<<1024, 256, 0, stream>>>(cnt, lists, n, e0, e1, e2, e3, ec);

    // exact tile grid: sum ceil(c_z/64) <= n/64 + 4 y-tiles, 4 col-panels each
    const int NT = (n + 63) / 64 + 4;
    k_gemm<<<NT * 4, 256, 0, stream>>>(cnt, lists, n, ec,
                                       pb0, pb1, pb2, pb3, out);
}